// Round 19
// baseline (138.754 us; speedup 1.0000x reference)
//
#include <hip/hip_runtime.h>

// NT-Xent loss, fused: never materialize the 8192x8192 similarity matrix.
// z = concat(z1,z2) [8192,256] f32 -> normalize -> fp8 e4m3 zn8 (ws, plain
// k-order). S = zn8 zn8^T via mfma_scale_f32_16x16x128_f8f6f4 (fp8/fp8,
// scale=1 -> identical numerics to plain fp8 MFMA at ~2.3x rate), fused
// per-row sum of exp(2*cos - 2) (fixed logsumexp max = 2 -> partials
// additive). nll_r = -pos_r + 2 + log(sum_r); out = mean(nll).
//
// R19 = R18's 64-rows/wave LDS-halving with R17's occupancy restored:
// CSPLIT=32 -> grid (32,32) = 1024 blocks = exactly 4 blocks/CU (16 waves/CU,
// no tail). R18 failed only because (32,16)=512 blocks = 2/CU. VGPR under the
// 128 cap: A=64 (K=128 fragments), epilogue split into two stripe-pairs so
// only 8 acc live (+16 b live across pairs) -> ~122 total. LDS read volume
// 512->256 MB (~5.1us/CU), below the 7.4us MFMA pipe.

#define NHALF 4096
#define N2 8192
#define D 256
#define CSPLIT 32
#define NPH 4       // phases per chunk; 4 tiles (64 cols) per phase
#define RPB 256     // rows per block (4 waves x 64)

typedef __attribute__((ext_vector_type(4))) float f32x4;
typedef __attribute__((ext_vector_type(8))) int i32x8;

__device__ __forceinline__ unsigned char f2fp8(float f) {
  // OCP e4m3fn, RNE; inputs |f| <= 1 (normalized rows): no sat/NaN path.
  unsigned int u = __float_as_uint(f);
  unsigned char s = (unsigned char)((u >> 24) & 0x80u);
  int e = (int)((u >> 23) & 0xffu) - 127;
  unsigned int m = u & 0x7fffffu;
  if (e >= -6) {
    unsigned int r = m + 0x7ffffu + ((m >> 20) & 1u);
    if (r >= 0x800000u) { r = 0; ++e; } else r >>= 20;
    return (unsigned char)(s | (unsigned int)((e + 7) << 3) | r);
  }
  int q = (int)rintf(fabsf(f) * 512.0f);
  return (unsigned char)(s | (unsigned int)q);
}

__device__ __forceinline__ void gload_lds16(const void* g, void* l) {
  __builtin_amdgcn_global_load_lds(
      (const __attribute__((address_space(1))) unsigned int*)g,
      (__attribute__((address_space(3))) unsigned int*)l, 16, 0, 0);
}

// ---------------- Kernel 1: row-normalize to fp8 (plain k-order) ----------------
__global__ __launch_bounds__(256) void norm_kernel(const float* __restrict__ z1,
                                                   const float* __restrict__ z2,
                                                   unsigned char* __restrict__ zn8) {
  const int lane = threadIdx.x & 63;
  const int row = blockIdx.x * 4 + (threadIdx.x >> 6);
  const float* src = (row < NHALF) ? (z1 + (size_t)row * D)
                                   : (z2 + (size_t)(row - NHALF) * D);
  const float4 v = *(const float4*)(src + lane * 4);
  float ss = v.x * v.x + v.y * v.y + v.z * v.z + v.w * v.w;
  #pragma unroll
  for (int m = 1; m < 64; m <<= 1) ss += __shfl_xor(ss, m);
  const float inv = 1.0f / fmaxf(sqrtf(ss), 1e-8f);
  unsigned int o = (unsigned int)f2fp8(v.x * inv) |
                   ((unsigned int)f2fp8(v.y * inv) << 8) |
                   ((unsigned int)f2fp8(v.z * inv) << 16) |
                   ((unsigned int)f2fp8(v.w * inv) << 24);
  *(unsigned int*)(zn8 + (size_t)row * D + lane * 4) = o;
}

// ---------------- Kernel 2: fused Gram + partial exp-sums ----------------
// grid (32 row-blocks, 32 col-chunks), 256 threads = 4 waves.
// Wave owns 64 rows = 4 stripes of 16; A in regs (64 VGPR); B in LDS.
// mfma_scale_f32_16x16x128_f8f6f4 (fp8/fp8, scale 2^0):
//   A/B lane l -> row/col (l&15), k-bytes 32*(l>>4)..+31 per instruction
//   (inst s covers k in [128s,128s+128)); D lane l -> col (l&15),
//   row 4*(l>>4)+g  (shape-determined -- R17-verified).
// LDS B: 2 buffers x [4 tiles][16 cols][256 B]; swizzle inner ^= (col&7)<<4
// on stage source AND each 16B ds_read independently (rule #21).
// Epilogue in two stripe-pairs: only 8 acc VGPRs live at a time.
__global__ __launch_bounds__(256, 4) void simlse_kernel(const unsigned char* __restrict__ zn8,
                                                        float* __restrict__ sum_ws,
                                                        float* __restrict__ pos_ws) {
  __shared__ __align__(16) char bsm[32768];  // 2 x 16 KB
  const int lane = threadIdx.x & 63;
  const int wave = threadIdx.x >> 6;
  const int r16 = lane & 15;
  const int h = lane >> 4;  // 0..3
  const int rowbase = blockIdx.x * RPB + wave * 64;
  const int cc = blockIdx.y;

  // A fragments: 4 stripes x 2 K-insts, 32B contiguous per lane (64 VGPR).
  i32x8 a[4][2];
  #pragma unroll
  for (int st = 0; st < 4; ++st) {
    const unsigned char* ap =
        zn8 + (size_t)(rowbase + st * 16 + r16) * D + h * 32;
    #pragma unroll
    for (int s = 0; s < 2; ++s) a[st][s] = *(const i32x8*)(ap + s * 128);
  }
  #pragma unroll
  for (int st = 0; st < 4; ++st)
    #pragma unroll
    for (int s = 0; s < 2; ++s) asm volatile("" : "+v"(a[st][s]));

  float lsum[4][4];
  #pragma unroll
  for (int st = 0; st < 4; ++st)
    #pragma unroll
    for (int g = 0; g < 4; ++g) lsum[st][g] = 0.0f;

  int dt[4], pt[4];
  #pragma unroll
  for (int st = 0; st < 4; ++st) {
    dt[st] = (rowbase + st * 16) >> 4;                      // diagonal tile
    pt[st] = ((rowbase + st * 16 + NHALF) & (N2 - 1)) >> 4; // positive tile
  }

  // Stage 4 tiles (16 KB) into LDS buffer. Linear y in [0,16384):
  // tile = y>>12, col = (y>>8)&15, inner = y&255; src inner ^= (col&7)<<4
  // (involution, 16B-aligned: XOR touches bits 4-6 only).
  auto stage = [&](int buf, int ph) {
    const int colbase = cc * 256 + ph * 64;
    #pragma unroll
    for (int s = 0; s < 4; ++s) {
      const int y = s * 4096 + wave * 1024 + lane * 16;
      const int col = (y >> 8) & 15;
      const int inner = (y & 255) ^ ((col & 7) << 4);
      const void* gp =
          zn8 + (size_t)(colbase + (y >> 12) * 16 + col) * D + inner;
      void* lp = bsm + buf * 16384 + s * 4096 + wave * 1024;  // +lane*16 by HW
      gload_lds16(gp, lp);
    }
  };

  // Per-stripe epilogue (acc consumed immediately -> only one pair live).
  auto epi = [&](int st, int ct, const f32x4& acc) {
    const bool isd = (ct == dt[st]);
    const bool isp = (ct == pt[st]);
    if (!isd && !isp) {
      #pragma unroll
      for (int g = 0; g < 4; ++g)
        lsum[st][g] += __expf(fmaf(acc[g], 2.0f, -2.0f));
    } else {
      #pragma unroll
      for (int g = 0; g < 4; ++g) {
        const int rl = (h << 2) + g;    // local row 0..15
        const bool hit = (r16 == rl);   // tile-diagonal element
        float e = __expf(fmaf(acc[g], 2.0f, -2.0f));
        if (isd && hit) e = 0.0f;       // mask self-similarity
        if (isp && hit) pos_ws[rowbase + st * 16 + rl] = acc[g] * 2.0f;
        lsum[st][g] += e;
      }
    }
  };

  stage(0, 0);
  __syncthreads();
  for (int ph = 0; ph < NPH; ++ph) {
    if (ph + 1 < NPH) stage((ph + 1) & 1, ph + 1);  // DMA overlaps compute
    const char* base = bsm + (ph & 1) * 16384;
    #pragma unroll
    for (int j = 0; j < 4; ++j) {
      const int ct = cc * 16 + ph * 4 + j;
      const char* tb = base + j * 4096 + r16 * 256;
      const int sw = (r16 & 7) << 4;
      // B fragments for both K-insts, live across both stripe-pairs (16 VGPR).
      i32x8 b[2];
      #pragma unroll
      for (int s = 0; s < 2; ++s) {
        const int o = s * 128 + h * 32;
        const int4 lo = *(const int4*)(tb + (o ^ sw));
        const int4 hi = *(const int4*)(tb + ((o + 16) ^ sw));
        b[s] = (i32x8){lo.x, lo.y, lo.z, lo.w, hi.x, hi.y, hi.z, hi.w};
      }
      // Stripe-pair 0 (stripes 0,1): 8 acc VGPRs live.
      {
        f32x4 acc0 = (f32x4){0.f, 0.f, 0.f, 0.f};
        f32x4 acc1 = (f32x4){0.f, 0.f, 0.f, 0.f};
        #pragma unroll
        for (int s = 0; s < 2; ++s) {
          acc0 = __builtin_amdgcn_mfma_scale_f32_16x16x128_f8f6f4(
              a[0][s], b[s], acc0, 0, 0, 0, 0x7F7F7F7F, 0, 0x7F7F7F7F);
          acc1 = __builtin_amdgcn_mfma_scale_f32_16x16x128_f8f6f4(
              a[1][s], b[s], acc1, 0, 0, 0, 0x7F7F7F7F, 0, 0x7F7F7F7F);
        }
        epi(0, ct, acc0);
        epi(1, ct, acc1);
      }
      // Stripe-pair 1 (stripes 2,3).
      {
        f32x4 acc0 = (f32x4){0.f, 0.f, 0.f, 0.f};
        f32x4 acc1 = (f32x4){0.f, 0.f, 0.f, 0.f};
        #pragma unroll
        for (int s = 0; s < 2; ++s) {
          acc0 = __builtin_amdgcn_mfma_scale_f32_16x16x128_f8f6f4(
              a[2][s], b[s], acc0, 0, 0, 0, 0x7F7F7F7F, 0, 0x7F7F7F7F);
          acc1 = __builtin_amdgcn_mfma_scale_f32_16x16x128_f8f6f4(
              a[3][s], b[s], acc1, 0, 0, 0, 0x7F7F7F7F, 0, 0x7F7F7F7F);
        }
        epi(2, ct, acc0);
        epi(3, ct, acc1);
      }
    }
    __syncthreads();  // drains DMA + LDS reads before buffer swap
  }

  // Reduce exp-sums across each 16-lane column group.
  #pragma unroll
  for (int st = 0; st < 4; ++st)
    #pragma unroll
    for (int g = 0; g < 4; ++g) {
      #pragma unroll
      for (int m = 1; m < 16; m <<= 1)
        lsum[st][g] += __shfl_xor(lsum[st][g], m);
    }
  if (r16 == 0) {
    #pragma unroll
    for (int st = 0; st < 4; ++st)
      #pragma unroll
      for (int g = 0; g < 4; ++g) {
        const int r = rowbase + st * 16 + (h << 2) + g;
        sum_ws[(size_t)r * CSPLIT + cc] = lsum[st][g];
      }
  }
}

// ---------------- Kernel 3a: per-row nll + per-block partial sum ----------------
__global__ __launch_bounds__(256) void nll_kernel(const float* __restrict__ sum_ws,
                                                  const float* __restrict__ pos_ws,
                                                  float* __restrict__ partial) {
  const int r = blockIdx.x * 256 + threadIdx.x;
  const float4* sp = (const float4*)(sum_ws + (size_t)r * CSPLIT);
  float t = 0.0f;
  #pragma unroll
  for (int i = 0; i < CSPLIT / 4; ++i) {
    const float4 v = sp[i];
    t += v.x + v.y + v.z + v.w;
  }
  float nll = -pos_ws[r] + 2.0f + __logf(t);
  #pragma unroll
  for (int m = 1; m < 64; m <<= 1) nll += __shfl_xor(nll, m);
  __shared__ float red[4];
  const int lane = threadIdx.x & 63;
  const int wave = threadIdx.x >> 6;
  if (lane == 0) red[wave] = nll;
  __syncthreads();
  if (threadIdx.x == 0) partial[blockIdx.x] = red[0] + red[1] + red[2] + red[3];
}

// ---------------- Kernel 3b: final mean ----------------
__global__ __launch_bounds__(64) void final_kernel(const float* __restrict__ partial,
                                                   float* __restrict__ out) {
  const int lane = threadIdx.x;
  float v = (lane < 32) ? partial[lane] : 0.0f;
  #pragma unroll
  for (int m = 1; m < 64; m <<= 1) v += __shfl_xor(v, m);
  if (lane == 0) out[0] = v * (1.0f / (float)N2);
}

extern "C" void kernel_launch(void* const* d_in, const int* in_sizes, int n_in,
                              void* d_out, int out_size, void* d_ws, size_t ws_size,
                              hipStream_t stream) {
  const float* z1 = (const float*)d_in[0];
  const float* z2 = (const float*)d_in[1];
  float* out = (float*)d_out;

  char* ws = (char*)d_ws;
  unsigned char* zn8 = (unsigned char*)ws;                  // 8192*256 = 2 MB
  float* sum_ws = (float*)(ws + (size_t)N2 * D);            // 8192*32*4 = 1 MB
  float* pos_ws = sum_ws + (size_t)N2 * CSPLIT;             // 8192*4 = 32 KB
  float* partial = pos_ws + N2;                             // 32 floats

  hipLaunchKernelGGL(norm_kernel, dim3(N2 / 4), dim3(256), 0, stream, z1, z2, zn8);
  hipLaunchKernelGGL(simlse_kernel, dim3(N2 / RPB, CSPLIT), dim3(256), 0, stream,
                     zn8, sum_ws, pos_ws);
  hipLaunchKernelGGL(nll_kernel, dim3(N2 / 256), dim3(256), 0, stream, sum_ws, pos_ws, partial);
  hipLaunchKernelGGL(final_kernel, dim3(1), dim3(64), 0, stream, partial, out);
}

// Round 20
// 43.036 us; speedup vs baseline: 3.2241x; 3.2241x over previous
//
#include <hip/hip_runtime.h>

// NT-Xent loss, fused: never materialize the 8192x8192 similarity matrix.
// z = concat(z1,z2) [8192,256] f32 -> normalize -> fp8 e4m3 zn8 (ws, plain
// k-order). S = zn8 zn8^T via mfma_scale_f32_16x16x128_f8f6f4 (fp8/fp8,
// scale=1 -> identical numerics to plain fp8 MFMA at ~2.3x rate), fused
// per-row sum of 2^(C2*cos - C2) = exp(2cos-2) (fixed logsumexp max = 2 ->
// partials additive). nll_r = -pos_r + 2 + log(sum_r); out = mean(nll).
//
// R20 = R17 (best verified: 37.4us total; 64-rows/wave and counted-vmcnt
// arcs BOTH closed after 4 spill regressions R8/R10/R14/R19 + occupancy loss
// R18) with two safe trims: (a) exp2f-folded epilogue deletes the hidden
// v_mul(log2e) inside __expf -- VALU is co-critical with MFMA; (b) sum_ws
// transposed to [cc][row] so nll's reads are fully coalesced.

#define NHALF 4096
#define N2 8192
#define D 256
#define CSPLIT 16
#define NPH 8       // phases per chunk; 4 tiles (64 cols) per phase
#define RPB 128     // rows per block (4 waves x 32)

typedef __attribute__((ext_vector_type(4))) float f32x4;
typedef __attribute__((ext_vector_type(8))) int i32x8;

#define C2E 2.885390081777927f  // 2*log2(e): exp(2a-2) = 2^(a*C2E - C2E)

__device__ __forceinline__ unsigned char f2fp8(float f) {
  // OCP e4m3fn, RNE; inputs |f| <= 1 (normalized rows): no sat/NaN path.
  unsigned int u = __float_as_uint(f);
  unsigned char s = (unsigned char)((u >> 24) & 0x80u);
  int e = (int)((u >> 23) & 0xffu) - 127;
  unsigned int m = u & 0x7fffffu;
  if (e >= -6) {
    unsigned int r = m + 0x7ffffu + ((m >> 20) & 1u);
    if (r >= 0x800000u) { r = 0; ++e; } else r >>= 20;
    return (unsigned char)(s | (unsigned int)((e + 7) << 3) | r);
  }
  int q = (int)rintf(fabsf(f) * 512.0f);
  return (unsigned char)(s | (unsigned int)q);
}

__device__ __forceinline__ void gload_lds16(const void* g, void* l) {
  __builtin_amdgcn_global_load_lds(
      (const __attribute__((address_space(1))) unsigned int*)g,
      (__attribute__((address_space(3))) unsigned int*)l, 16, 0, 0);
}

// ---------------- Kernel 1: row-normalize to fp8 (plain k-order) ----------------
__global__ __launch_bounds__(256) void norm_kernel(const float* __restrict__ z1,
                                                   const float* __restrict__ z2,
                                                   unsigned char* __restrict__ zn8) {
  const int lane = threadIdx.x & 63;
  const int row = blockIdx.x * 4 + (threadIdx.x >> 6);
  const float* src = (row < NHALF) ? (z1 + (size_t)row * D)
                                   : (z2 + (size_t)(row - NHALF) * D);
  const float4 v = *(const float4*)(src + lane * 4);
  float ss = v.x * v.x + v.y * v.y + v.z * v.z + v.w * v.w;
  #pragma unroll
  for (int m = 1; m < 64; m <<= 1) ss += __shfl_xor(ss, m);
  const float inv = 1.0f / fmaxf(sqrtf(ss), 1e-8f);
  unsigned int o = (unsigned int)f2fp8(v.x * inv) |
                   ((unsigned int)f2fp8(v.y * inv) << 8) |
                   ((unsigned int)f2fp8(v.z * inv) << 16) |
                   ((unsigned int)f2fp8(v.w * inv) << 24);
  *(unsigned int*)(zn8 + (size_t)row * D + lane * 4) = o;
}

// ---------------- Kernel 2: fused Gram + partial exp-sums ----------------
// grid (64 row-blocks, 16 col-chunks), 256 threads = 4 waves.
// Wave owns 32 rows = 2 stripes of 16; A in regs (32 VGPR); B in LDS.
// mfma_scale_f32_16x16x128_f8f6f4 (fp8/fp8, scale 2^0):
//   A/B lane l -> row/col (l&15), k-bytes 32*(l>>4)..+31 per instruction
//   (inst s covers k in [128s,128s+128)); D lane l -> col (l&15),
//   row 4*(l>>4)+g  (shape-determined -- R17-verified).
// LDS B: 2 buffers x [4 tiles][16 cols][256 B]; swizzle inner ^= (col&7)<<4
// on stage source AND each 16B ds_read independently (rule #21).
__global__ __launch_bounds__(256, 4) void simlse_kernel(const unsigned char* __restrict__ zn8,
                                                        float* __restrict__ sum_ws,
                                                        float* __restrict__ pos_ws) {
  __shared__ __align__(16) char bsm[32768];  // 2 x 16 KB
  const int lane = threadIdx.x & 63;
  const int wave = threadIdx.x >> 6;
  const int r16 = lane & 15;
  const int h = lane >> 4;  // 0..3
  const int rowbase = blockIdx.x * RPB + wave * 32;
  const int cc = blockIdx.y;

  // A fragments: 2 stripes x 2 K-insts, 32B contiguous per lane (32 VGPR).
  i32x8 a[2][2];
  #pragma unroll
  for (int st = 0; st < 2; ++st) {
    const unsigned char* ap =
        zn8 + (size_t)(rowbase + st * 16 + r16) * D + h * 32;
    #pragma unroll
    for (int s = 0; s < 2; ++s) a[st][s] = *(const i32x8*)(ap + s * 128);
  }
  #pragma unroll
  for (int st = 0; st < 2; ++st)
    #pragma unroll
    for (int s = 0; s < 2; ++s) asm volatile("" : "+v"(a[st][s]));

  float lsum[2][4];
  #pragma unroll
  for (int st = 0; st < 2; ++st)
    #pragma unroll
    for (int g = 0; g < 4; ++g) lsum[st][g] = 0.0f;

  int dt[2], pt[2];
  #pragma unroll
  for (int st = 0; st < 2; ++st) {
    dt[st] = (rowbase + st * 16) >> 4;                      // diagonal tile
    pt[st] = ((rowbase + st * 16 + NHALF) & (N2 - 1)) >> 4; // positive tile
  }

  // Stage 4 tiles (16 KB) into LDS buffer. Linear y in [0,16384):
  // tile = y>>12, col = (y>>8)&15, inner = y&255; src inner ^= (col&7)<<4
  // (involution, 16B-aligned: XOR touches bits 4-6 only).
  auto stage = [&](int buf, int ph) {
    const int colbase = cc * 512 + ph * 64;
    #pragma unroll
    for (int s = 0; s < 4; ++s) {
      const int y = s * 4096 + wave * 1024 + lane * 16;
      const int col = (y >> 8) & 15;
      const int inner = (y & 255) ^ ((col & 7) << 4);
      const void* gp =
          zn8 + (size_t)(colbase + (y >> 12) * 16 + col) * D + inner;
      void* lp = bsm + buf * 16384 + s * 4096 + wave * 1024;  // +lane*16 by HW
      gload_lds16(gp, lp);
    }
  };

  stage(0, 0);
  __syncthreads();
  for (int ph = 0; ph < NPH; ++ph) {
    if (ph + 1 < NPH) stage((ph + 1) & 1, ph + 1);  // DMA overlaps compute
    const char* base = bsm + (ph & 1) * 16384;
    #pragma unroll
    for (int j = 0; j < 4; ++j) {
      const int ct = cc * 32 + ph * 4 + j;
      const char* tb = base + j * 4096 + r16 * 256;
      const int sw = (r16 & 7) << 4;
      f32x4 acc0 = (f32x4){0.f, 0.f, 0.f, 0.f};
      f32x4 acc1 = (f32x4){0.f, 0.f, 0.f, 0.f};
      #pragma unroll
      for (int s = 0; s < 2; ++s) {
        // 32B B-fragment = two b128, each independently XOR-swizzled
        // (bit-4 swizzle would otherwise swap the 16B halves).
        const int o = s * 128 + h * 32;
        const int4 lo = *(const int4*)(tb + (o ^ sw));
        const int4 hi = *(const int4*)(tb + ((o + 16) ^ sw));
        const i32x8 b = {lo.x, lo.y, lo.z, lo.w, hi.x, hi.y, hi.z, hi.w};
        acc0 = __builtin_amdgcn_mfma_scale_f32_16x16x128_f8f6f4(
            a[0][s], b, acc0, 0, 0, 0, 0x7F7F7F7F, 0, 0x7F7F7F7F);
        acc1 = __builtin_amdgcn_mfma_scale_f32_16x16x128_f8f6f4(
            a[1][s], b, acc1, 0, 0, 0, 0x7F7F7F7F, 0, 0x7F7F7F7F);
      }
      #pragma unroll
      for (int st = 0; st < 2; ++st) {
        const f32x4& acc = st ? acc1 : acc0;
        const bool isd = (ct == dt[st]);
        const bool isp = (ct == pt[st]);
        if (!isd && !isp) {
          #pragma unroll
          for (int g = 0; g < 4; ++g)
            lsum[st][g] += exp2f(fmaf(acc[g], C2E, -C2E));  // exp(2a-2)
        } else {
          #pragma unroll
          for (int g = 0; g < 4; ++g) {
            const int rl = (h << 2) + g;    // local row 0..15
            const bool hit = (r16 == rl);   // tile-diagonal element
            float e = exp2f(fmaf(acc[g], C2E, -C2E));
            if (isd && hit) e = 0.0f;       // mask self-similarity
            if (isp && hit) pos_ws[rowbase + st * 16 + rl] = acc[g] * 2.0f;
            lsum[st][g] += e;
          }
        }
      }
    }
    __syncthreads();  // drains DMA + LDS reads before buffer swap
  }

  // Reduce exp-sums across each 16-lane column group.
  #pragma unroll
  for (int st = 0; st < 2; ++st)
    #pragma unroll
    for (int g = 0; g < 4; ++g) {
      #pragma unroll
      for (int m = 1; m < 16; m <<= 1)
        lsum[st][g] += __shfl_xor(lsum[st][g], m);
    }
  if (r16 == 0) {
    #pragma unroll
    for (int st = 0; st < 2; ++st)
      #pragma unroll
      for (int g = 0; g < 4; ++g) {
        const int r = rowbase + st * 16 + (h << 2) + g;
        sum_ws[(size_t)cc * N2 + r] = lsum[st][g];  // [cc][row]: coalesced nll
      }
  }
}

// ---------------- Kernel 3a: per-row nll + per-block partial sum ----------------
__global__ __launch_bounds__(256) void nll_kernel(const float* __restrict__ sum_ws,
                                                  const float* __restrict__ pos_ws,
                                                  float* __restrict__ partial) {
  const int r = blockIdx.x * 256 + threadIdx.x;
  float t = 0.0f;
  #pragma unroll
  for (int c = 0; c < CSPLIT; ++c)
    t += sum_ws[(size_t)c * N2 + r];  // coalesced across threads
  float nll = -pos_ws[r] + 2.0f + __logf(t);
  #pragma unroll
  for (int m = 1; m < 64; m <<= 1) nll += __shfl_xor(nll, m);
  __shared__ float red[4];
  const int lane = threadIdx.x & 63;
  const int wave = threadIdx.x >> 6;
  if (lane == 0) red[wave] = nll;
  __syncthreads();
  if (threadIdx.x == 0) partial[blockIdx.x] = red[0] + red[1] + red[2] + red[3];
}

// ---------------- Kernel 3b: final mean ----------------
__global__ __launch_bounds__(64) void final_kernel(const float* __restrict__ partial,
                                                   float* __restrict__ out) {
  const int lane = threadIdx.x;
  float v = (lane < 32) ? partial[lane] : 0.0f;
  #pragma unroll
  for (int m = 1; m < 64; m <<= 1) v += __shfl_xor(v, m);
  if (lane == 0) out[0] = v * (1.0f / (float)N2);
}

extern "C" void kernel_launch(void* const* d_in, const int* in_sizes, int n_in,
                              void* d_out, int out_size, void* d_ws, size_t ws_size,
                              hipStream_t stream) {
  const float* z1 = (const float*)d_in[0];
  const float* z2 = (const float*)d_in[1];
  float* out = (float*)d_out;

  char* ws = (char*)d_ws;
  unsigned char* zn8 = (unsigned char*)ws;                  // 8192*256 = 2 MB
  float* sum_ws = (float*)(ws + (size_t)N2 * D);            // 16*8192*4 = 512 KB
  float* pos_ws = sum_ws + (size_t)N2 * CSPLIT;             // 8192*4 = 32 KB
  float* partial = pos_ws + N2;                             // 32 floats

  hipLaunchKernelGGL(norm_kernel, dim3(N2 / 4), dim3(256), 0, stream, z1, z2, zn8);
  hipLaunchKernelGGL(simlse_kernel, dim3(N2 / RPB, CSPLIT), dim3(256), 0, stream,
                     zn8, sum_ws, pos_ws);
  hipLaunchKernelGGL(nll_kernel, dim3(N2 / 256), dim3(256), 0, stream, sum_ws, pos_ws, partial);
  hipLaunchKernelGGL(final_kernel, dim3(1), dim3(64), 0, stream, partial, out);
}

// Round 21
// 37.602 us; speedup vs baseline: 3.6901x; 1.1445x over previous
//
#include <hip/hip_runtime.h>

// NT-Xent loss, fused: never materialize the 8192x8192 similarity matrix.
// z = concat(z1,z2) [8192,256] f32 -> normalize -> fp8 e4m3 zn8 (ws, plain
// k-order). S = zn8 zn8^T via mfma_scale_f32_16x16x128_f8f6f4 (fp8/fp8,
// scale=1 -> identical numerics to plain fp8 MFMA at ~2.3x rate), fused
// per-row sum of exp(2*cos - 2) (fixed logsumexp max = 2 -> partials
// additive). nll_r = -pos_r + 2 + log(sum_r); out = mean(nll).
//
// R21 = R17 epilogue restored (__expf; R20's exp2f lowered to the PRECISE
// OCML exp2 path, not a bare v_exp -> +15% regression) + R20's sum_ws
// [cc][row] transpose kept (coalesced nll reads; isolating its delta).
// Structural ledger: counted-vmcnt closed (3 spills), 64-rows/wave closed
// (3 spills + 1 occupancy loss), triangularization closed (2x overhead).

#define NHALF 4096
#define N2 8192
#define D 256
#define CSPLIT 16
#define NPH 8       // phases per chunk; 4 tiles (64 cols) per phase
#define RPB 128     // rows per block (4 waves x 32)

typedef __attribute__((ext_vector_type(4))) float f32x4;
typedef __attribute__((ext_vector_type(8))) int i32x8;

__device__ __forceinline__ unsigned char f2fp8(float f) {
  // OCP e4m3fn, RNE; inputs |f| <= 1 (normalized rows): no sat/NaN path.
  unsigned int u = __float_as_uint(f);
  unsigned char s = (unsigned char)((u >> 24) & 0x80u);
  int e = (int)((u >> 23) & 0xffu) - 127;
  unsigned int m = u & 0x7fffffu;
  if (e >= -6) {
    unsigned int r = m + 0x7ffffu + ((m >> 20) & 1u);
    if (r >= 0x800000u) { r = 0; ++e; } else r >>= 20;
    return (unsigned char)(s | (unsigned int)((e + 7) << 3) | r);
  }
  int q = (int)rintf(fabsf(f) * 512.0f);
  return (unsigned char)(s | (unsigned int)q);
}

__device__ __forceinline__ void gload_lds16(const void* g, void* l) {
  __builtin_amdgcn_global_load_lds(
      (const __attribute__((address_space(1))) unsigned int*)g,
      (__attribute__((address_space(3))) unsigned int*)l, 16, 0, 0);
}

// ---------------- Kernel 1: row-normalize to fp8 (plain k-order) ----------------
__global__ __launch_bounds__(256) void norm_kernel(const float* __restrict__ z1,
                                                   const float* __restrict__ z2,
                                                   unsigned char* __restrict__ zn8) {
  const int lane = threadIdx.x & 63;
  const int row = blockIdx.x * 4 + (threadIdx.x >> 6);
  const float* src = (row < NHALF) ? (z1 + (size_t)row * D)
                                   : (z2 + (size_t)(row - NHALF) * D);
  const float4 v = *(const float4*)(src + lane * 4);
  float ss = v.x * v.x + v.y * v.y + v.z * v.z + v.w * v.w;
  #pragma unroll
  for (int m = 1; m < 64; m <<= 1) ss += __shfl_xor(ss, m);
  const float inv = 1.0f / fmaxf(sqrtf(ss), 1e-8f);
  unsigned int o = (unsigned int)f2fp8(v.x * inv) |
                   ((unsigned int)f2fp8(v.y * inv) << 8) |
                   ((unsigned int)f2fp8(v.z * inv) << 16) |
                   ((unsigned int)f2fp8(v.w * inv) << 24);
  *(unsigned int*)(zn8 + (size_t)row * D + lane * 4) = o;
}

// ---------------- Kernel 2: fused Gram + partial exp-sums ----------------
// grid (64 row-blocks, 16 col-chunks), 256 threads = 4 waves.
// Wave owns 32 rows = 2 stripes of 16; A in regs (32 VGPR); B in LDS.
// mfma_scale_f32_16x16x128_f8f6f4 (fp8/fp8, scale 2^0):
//   A/B lane l -> row/col (l&15), k-bytes 32*(l>>4)..+31 per instruction
//   (inst s covers k in [128s,128s+128)); D lane l -> col (l&15),
//   row 4*(l>>4)+g  (shape-determined -- R17-verified).
// LDS B: 2 buffers x [4 tiles][16 cols][256 B]; swizzle inner ^= (col&7)<<4
// on stage source AND each 16B ds_read independently (rule #21).
__global__ __launch_bounds__(256, 4) void simlse_kernel(const unsigned char* __restrict__ zn8,
                                                        float* __restrict__ sum_ws,
                                                        float* __restrict__ pos_ws) {
  __shared__ __align__(16) char bsm[32768];  // 2 x 16 KB
  const int lane = threadIdx.x & 63;
  const int wave = threadIdx.x >> 6;
  const int r16 = lane & 15;
  const int h = lane >> 4;  // 0..3
  const int rowbase = blockIdx.x * RPB + wave * 32;
  const int cc = blockIdx.y;

  // A fragments: 2 stripes x 2 K-insts, 32B contiguous per lane (32 VGPR).
  i32x8 a[2][2];
  #pragma unroll
  for (int st = 0; st < 2; ++st) {
    const unsigned char* ap =
        zn8 + (size_t)(rowbase + st * 16 + r16) * D + h * 32;
    #pragma unroll
    for (int s = 0; s < 2; ++s) a[st][s] = *(const i32x8*)(ap + s * 128);
  }
  #pragma unroll
  for (int st = 0; st < 2; ++st)
    #pragma unroll
    for (int s = 0; s < 2; ++s) asm volatile("" : "+v"(a[st][s]));

  float lsum[2][4];
  #pragma unroll
  for (int st = 0; st < 2; ++st)
    #pragma unroll
    for (int g = 0; g < 4; ++g) lsum[st][g] = 0.0f;

  int dt[2], pt[2];
  #pragma unroll
  for (int st = 0; st < 2; ++st) {
    dt[st] = (rowbase + st * 16) >> 4;                      // diagonal tile
    pt[st] = ((rowbase + st * 16 + NHALF) & (N2 - 1)) >> 4; // positive tile
  }

  // Stage 4 tiles (16 KB) into LDS buffer. Linear y in [0,16384):
  // tile = y>>12, col = (y>>8)&15, inner = y&255; src inner ^= (col&7)<<4
  // (involution, 16B-aligned: XOR touches bits 4-6 only).
  auto stage = [&](int buf, int ph) {
    const int colbase = cc * 512 + ph * 64;
    #pragma unroll
    for (int s = 0; s < 4; ++s) {
      const int y = s * 4096 + wave * 1024 + lane * 16;
      const int col = (y >> 8) & 15;
      const int inner = (y & 255) ^ ((col & 7) << 4);
      const void* gp =
          zn8 + (size_t)(colbase + (y >> 12) * 16 + col) * D + inner;
      void* lp = bsm + buf * 16384 + s * 4096 + wave * 1024;  // +lane*16 by HW
      gload_lds16(gp, lp);
    }
  };

  stage(0, 0);
  __syncthreads();
  for (int ph = 0; ph < NPH; ++ph) {
    if (ph + 1 < NPH) stage((ph + 1) & 1, ph + 1);  // DMA overlaps compute
    const char* base = bsm + (ph & 1) * 16384;
    #pragma unroll
    for (int j = 0; j < 4; ++j) {
      const int ct = cc * 32 + ph * 4 + j;
      const char* tb = base + j * 4096 + r16 * 256;
      const int sw = (r16 & 7) << 4;
      f32x4 acc0 = (f32x4){0.f, 0.f, 0.f, 0.f};
      f32x4 acc1 = (f32x4){0.f, 0.f, 0.f, 0.f};
      #pragma unroll
      for (int s = 0; s < 2; ++s) {
        // 32B B-fragment = two b128, each independently XOR-swizzled
        // (bit-4 swizzle would otherwise swap the 16B halves).
        const int o = s * 128 + h * 32;
        const int4 lo = *(const int4*)(tb + (o ^ sw));
        const int4 hi = *(const int4*)(tb + ((o + 16) ^ sw));
        const i32x8 b = {lo.x, lo.y, lo.z, lo.w, hi.x, hi.y, hi.z, hi.w};
        acc0 = __builtin_amdgcn_mfma_scale_f32_16x16x128_f8f6f4(
            a[0][s], b, acc0, 0, 0, 0, 0x7F7F7F7F, 0, 0x7F7F7F7F);
        acc1 = __builtin_amdgcn_mfma_scale_f32_16x16x128_f8f6f4(
            a[1][s], b, acc1, 0, 0, 0, 0x7F7F7F7F, 0, 0x7F7F7F7F);
      }
      #pragma unroll
      for (int st = 0; st < 2; ++st) {
        const f32x4& acc = st ? acc1 : acc0;
        const bool isd = (ct == dt[st]);
        const bool isp = (ct == pt[st]);
        if (!isd && !isp) {
          #pragma unroll
          for (int g = 0; g < 4; ++g)
            lsum[st][g] += __expf(fmaf(acc[g], 2.0f, -2.0f));
        } else {
          #pragma unroll
          for (int g = 0; g < 4; ++g) {
            const int rl = (h << 2) + g;    // local row 0..15
            const bool hit = (r16 == rl);   // tile-diagonal element
            float e = __expf(fmaf(acc[g], 2.0f, -2.0f));
            if (isd && hit) e = 0.0f;       // mask self-similarity
            if (isp && hit) pos_ws[rowbase + st * 16 + rl] = acc[g] * 2.0f;
            lsum[st][g] += e;
          }
        }
      }
    }
    __syncthreads();  // drains DMA + LDS reads before buffer swap
  }

  // Reduce exp-sums across each 16-lane column group.
  #pragma unroll
  for (int st = 0; st < 2; ++st)
    #pragma unroll
    for (int g = 0; g < 4; ++g) {
      #pragma unroll
      for (int m = 1; m < 16; m <<= 1)
        lsum[st][g] += __shfl_xor(lsum[st][g], m);
    }
  if (r16 == 0) {
    #pragma unroll
    for (int st = 0; st < 2; ++st)
      #pragma unroll
      for (int g = 0; g < 4; ++g) {
        const int r = rowbase + st * 16 + (h << 2) + g;
        sum_ws[(size_t)cc * N2 + r] = lsum[st][g];  // [cc][row]: coalesced nll
      }
  }
}

// ---------------- Kernel 3a: per-row nll + per-block partial sum ----------------
__global__ __launch_bounds__(256) void nll_kernel(const float* __restrict__ sum_ws,
                                                  const float* __restrict__ pos_ws,
                                                  float* __restrict__ partial) {
  const int r = blockIdx.x * 256 + threadIdx.x;
  float t = 0.0f;
  #pragma unroll
  for (int c = 0; c < CSPLIT; ++c)
    t += sum_ws[(size_t)c * N2 + r];  // coalesced across threads
  float nll = -pos_ws[r] + 2.0f + __logf(t);
  #pragma unroll
  for (int m = 1; m < 64; m <<= 1) nll += __shfl_xor(nll, m);
  __shared__ float red[4];
  const int lane = threadIdx.x & 63;
  const int wave = threadIdx.x >> 6;
  if (lane == 0) red[wave] = nll;
  __syncthreads();
  if (threadIdx.x == 0) partial[blockIdx.x] = red[0] + red[1] + red[2] + red[3];
}

// ---------------- Kernel 3b: final mean ----------------
__global__ __launch_bounds__(64) void final_kernel(const float* __restrict__ partial,
                                                   float* __restrict__ out) {
  const int lane = threadIdx.x;
  float v = (lane < 32) ? partial[lane] : 0.0f;
  #pragma unroll
  for (int m = 1; m < 64; m <<= 1) v += __shfl_xor(v, m);
  if (lane == 0) out[0] = v * (1.0f / (float)N2);
}

extern "C" void kernel_launch(void* const* d_in, const int* in_sizes, int n_in,
                              void* d_out, int out_size, void* d_ws, size_t ws_size,
                              hipStream_t stream) {
  const float* z1 = (const float*)d_in[0];
  const float* z2 = (const float*)d_in[1];
  float* out = (float*)d_out;

  char* ws = (char*)d_ws;
  unsigned char* zn8 = (unsigned char*)ws;                  // 8192*256 = 2 MB
  float* sum_ws = (float*)(ws + (size_t)N2 * D);            // 16*8192*4 = 512 KB
  float* pos_ws = sum_ws + (size_t)N2 * CSPLIT;             // 8192*4 = 32 KB
  float* partial = pos_ws + N2;                             // 32 floats

  hipLaunchKernelGGL(norm_kernel, dim3(N2 / 4), dim3(256), 0, stream, z1, z2, zn8);
  hipLaunchKernelGGL(simlse_kernel, dim3(N2 / RPB, CSPLIT), dim3(256), 0, stream,
                     zn8, sum_ws, pos_ws);
  hipLaunchKernelGGL(nll_kernel, dim3(N2 / 256), dim3(256), 0, stream, sum_ws, pos_ws, partial);
  hipLaunchKernelGGL(final_kernel, dim3(1), dim3(64), 0, stream, partial, out);
}